// Round 6
// baseline (471.031 us; speedup 1.0000x reference)
//
#include <hip/hip_runtime.h>
#include <hip/hip_bf16.h>

// HyperbolicGraphConstructor R6:
//  - fused_kernel: R5's barrier-free permuted-j register dataflow, now with
//    16-wave (1024-thread) blocks -> 16 waves/CU = 4 waves/SIMD (was 2).
//    Each wave covers 16 j-steps. __launch_bounds__(1024) caps VGPR at 128.
//  - prep/gram/rowcoef unchanged.

typedef __attribute__((ext_vector_type(8))) short short8;
typedef __attribute__((ext_vector_type(4))) float f32x4;

#define MAXN 0.996f   /* (1 - 4e-3)/sqrt(c) */

__device__ __forceinline__ float artanh_clip(float x) {
    x = fminf(x, 1.0f - 1e-7f);
    x = fmaxf(x, -1.0f + 1e-7f);
    return 0.5f * logf((1.0f + x) / (1.0f - x));
}

__device__ __forceinline__ float red8(float v) {
    v += __shfl_xor(v, 1);
    v += __shfl_xor(v, 2);
    v += __shfl_xor(v, 4);
    return v;
}

__device__ __forceinline__ float red64(float v) {
#pragma unroll
    for (int m = 1; m < 64; m <<= 1) v += __shfl_xor(v, m);
    return v;
}

__device__ __forceinline__ unsigned short f2bf(float f) {
    __hip_bfloat16 h = __float2bfloat16(f);
    return *reinterpret_cast<unsigned short*>(&h);
}

__device__ __forceinline__ float bf2f(unsigned short u) {
    __hip_bfloat16 h;
    *reinterpret_cast<unsigned short*>(&h) = u;
    return __bfloat162float(h);
}

// ---------------------------------------------------------------- prep ------
// grid (256, 3), block 256: y=0 -> nv1 (emb1,W1,b1); y=1 -> nv2; y=2 -> xt.
__global__ __launch_bounds__(256) void prep_kernel(
    const int* __restrict__ idx, const float* __restrict__ x,
    const float* __restrict__ emb1, const float* __restrict__ emb2,
    const float* __restrict__ W1, const float* __restrict__ W2,
    const float* __restrict__ b1, const float* __restrict__ b2,
    unsigned short* __restrict__ nv1b, unsigned short* __restrict__ nv2b,
    unsigned short* __restrict__ xtT,
    float* __restrict__ xn1, float* __restrict__ xn2) {
    const int which = blockIdx.y;
    const int tid = threadIdx.x;
    const int rblk = blockIdx.x * 32;

    if (which == 2) {
        __shared__ float xv[32 * 132];
        const int r = tid >> 3, s = tid & 7;
        float ev[16];
        float p2 = 0.f;
#pragma unroll
        for (int kk = 0; kk < 16; ++kk) {
            float e = x[(rblk + r) * 128 + s + kk * 8];
            ev[kk] = e;
            p2 += e * e;
        }
        const float n = fmaxf(sqrtf(red8(p2)), 1e-15f);
        const float scl = artanh_clip(n) / n;
#pragma unroll
        for (int kk = 0; kk < 16; ++kk) xv[r * 132 + s + kk * 8] = ev[kk] * scl;
        __syncthreads();
        const int k = tid >> 1, h = tid & 1;
        short8 o0, o1;
#pragma unroll
        for (int j = 0; j < 8; ++j) o0[j] = (short)f2bf(xv[(h * 16 + j) * 132 + k]);
#pragma unroll
        for (int j = 0; j < 8; ++j) o1[j] = (short)f2bf(xv[(h * 16 + 8 + j) * 132 + k]);
        *reinterpret_cast<short8*>(&xtT[k * 8192 + rblk + h * 16]) = o0;
        *reinterpret_cast<short8*>(&xtT[k * 8192 + rblk + h * 16 + 8]) = o1;
        return;
    }

    __shared__ __align__(16) float uL[32 * 132];
    __shared__ float mxL[32 * 132];
    __shared__ float xnL[32];
    __shared__ float hbL[128];
    __shared__ float s2s[4];

    const float* emb = which ? emb2 : emb1;
    const float* W = which ? W2 : W1;
    const float* b = which ? b2 : b1;
    unsigned short* nvb = which ? nv2b : nv1b;
    float* xno = which ? xn2 : xn1;

    float bv = (tid < 128) ? b[tid] : 0.f;
    float ssq = red64(bv * bv);
    if ((tid & 63) == 0) s2s[tid >> 6] = ssq;
    __syncthreads();
    const float bn = fmaxf(sqrtf(s2s[0] + s2s[1]), 1e-15f);
    const float bth = tanhf(bn);
    const float bnu = fmaxf(bth, 1e-15f);
    const float bps = (bnu > MAXN) ? (MAXN / bnu) : 1.0f;
    if (tid < 128) hbL[tid] = bv * (bth / bn) * bps;
    const float hbn = fminf(bnu, MAXN);
    const float y2 = hbn * hbn;

    const int r = tid >> 3, s = tid & 7;
    const int row = rblk + r;
    const int src = idx[row];
    float ev[16];
    float p2 = 0.f;
#pragma unroll
    for (int kk = 0; kk < 16; ++kk) {
        float e = emb[src * 128 + s + kk * 8];
        ev[kk] = e;
        p2 += e * e;
    }
    float n2 = red8(p2);
    float n = fmaxf(sqrtf(n2), 1e-15f);
    float th = tanhf(n);
    float nu = fmaxf(th, 1e-15f);
    float ps = (nu > MAXN) ? (MAXN / nu) : 1.0f;
    float sc0 = (th / n) * ps;
#pragma unroll
    for (int kk = 0; kk < 16; ++kk) uL[r * 132 + s + kk * 8] = ev[kk] * sc0;
    if (s == 0) xnL[r] = fmaxf(nu * ps, 1e-15f);
    __syncthreads();

    const int o = tid & 127, rb = tid >> 7;
    float mxv[16];
#pragma unroll
    for (int rr = 0; rr < 16; ++rr) mxv[rr] = 0.f;
    for (int k4 = 0; k4 < 128; k4 += 4) {
        const float4 wv = *reinterpret_cast<const float4*>(&W[o * 128 + k4]);
#pragma unroll
        for (int rr = 0; rr < 16; ++rr) {
            const float4 uv = *reinterpret_cast<const float4*>(&uL[(rb + rr * 2) * 132 + k4]);
            mxv[rr] += uv.x * wv.x + uv.y * wv.y + uv.z * wv.z + uv.w * wv.w;
        }
    }
#pragma unroll
    for (int rr = 0; rr < 16; ++rr) mxL[(rb + rr * 2) * 132 + o] = mxv[rr];
    __syncthreads();

    float mx[16];
    float m2 = 0.f;
#pragma unroll
    for (int kk = 0; kk < 16; ++kk) {
        mx[kk] = mxL[r * 132 + s + kk * 8];
        m2 += mx[kk] * mx[kk];
    }
    float mxn = fmaxf(sqrtf(red8(m2)), 1e-15f);
    float xnv = xnL[r];
    float tt = tanhf(mxn / xnv * artanh_clip(xnv));
    float nres = fmaxf(tt, 1e-15f);
    float ps2 = (nres > MAXN) ? (MAXN / nres) : 1.0f;
    float s2 = (tt / mxn) * ps2;
    float mvn = nres * ps2;
    float x2 = mvn * mvn;
    float xyp = 0.f;
    float mv[16];
#pragma unroll
    for (int kk = 0; kk < 16; ++kk) {
        mv[kk] = mx[kk] * s2;
        xyp += mv[kk] * hbL[s + kk * 8];
    }
    float xy = red8(xyp);
    float cA = 1.f + 2.f * xy + y2;
    float cB = 1.f - x2;
    float rden = 1.f / fmaxf(1.f + 2.f * xy + x2 * y2, 1e-15f);
    float r2v[16];
    float q2 = 0.f;
#pragma unroll
    for (int kk = 0; kk < 16; ++kk) {
        float v = (cA * mv[kk] + cB * hbL[s + kk * 8]) * rden;
        r2v[kk] = v;
        q2 += v * v;
    }
    float nr2 = fmaxf(sqrtf(red8(q2)), 1e-15f);
    float ps3 = (nr2 > MAXN) ? (MAXN / nr2) : 1.0f;
#pragma unroll
    for (int kk = 0; kk < 16; ++kk) nvb[row * 128 + s + kk * 8] = f2bf(r2v[kk] * ps3);
    if (s == 0) xno[row] = fmaxf((nr2 > MAXN) ? MAXN : nr2, 1e-15f);
}

// ---------------------------------------------------------------- gram ------
__global__ __launch_bounds__(256) void gram_kernel(const unsigned short* __restrict__ nv1b,
                                                   const unsigned short* __restrict__ nv2b,
                                                   float* __restrict__ G) {
    __shared__ float Ab[64 * 33], Bb[64 * 33];
    const int tile = blockIdx.x, mat = blockIdx.y, kc = blockIdx.z;
    const int ta = (tile & 3) * 32, tb = (tile >> 2) * 32;
    const unsigned short* Am = (mat == 1) ? nv2b : nv1b;
    const unsigned short* Bm = (mat == 0) ? nv1b : nv2b;
    const int tid = threadIdx.x;
    const int oa = tid & 31, obb = (tid >> 5) * 4;
    float acc[4] = {0.f, 0.f, 0.f, 0.f};
    for (int sc = 0; sc < 16; ++sc) {
        const int r0 = kc * 1024 + sc * 64;
        for (int i0 = tid; i0 < 2048; i0 += 256) {
            int rr = i0 >> 5, cc = i0 & 31;
            Ab[rr * 33 + cc] = bf2f(Am[(r0 + rr) * 128 + ta + cc]);
            Bb[rr * 33 + cc] = bf2f(Bm[(r0 + rr) * 128 + tb + cc]);
        }
        __syncthreads();
#pragma unroll 4
        for (int rr = 0; rr < 64; ++rr) {
            float av = Ab[rr * 33 + oa];
#pragma unroll
            for (int i = 0; i < 4; ++i) acc[i] += av * Bb[rr * 33 + obb + i];
        }
        __syncthreads();
    }
#pragma unroll
    for (int i = 0; i < 4; ++i)
        atomicAdd(&G[mat * 16384 + (ta + oa) * 128 + tb + obb + i], acc[i]);
}

// ---------------------------------------------------------------- rowcoef ---
__global__ __launch_bounds__(256) void rowcoef_kernel(
    const float* __restrict__ G, const float* __restrict__ xn1, const float* __restrict__ xn2,
    const unsigned short* __restrict__ nv1b, const unsigned short* __restrict__ nv2b,
    float* __restrict__ P, float* __restrict__ Q) {
    __shared__ __align__(16) float v1L[32 * 132];
    __shared__ __align__(16) float v2L[32 * 132];
    __shared__ float tL[32 * 132];
    __shared__ float RCX[3][32];
    const int tid = threadIdx.x;
    const int rblk = blockIdx.x * 32;
    for (int i = tid; i < 4096; i += 256) {
        int r = i >> 7, c = i & 127;
        v1L[r * 132 + c] = bf2f(nv1b[(rblk + r) * 128 + c]);
        v2L[r * 132 + c] = bf2f(nv2b[(rblk + r) * 128 + c]);
    }
    __syncthreads();
    const int o = tid & 127, rb = tid >> 7;
    const int rA = tid >> 3, sA = tid & 7;
    for (int mat = 0; mat < 3; ++mat) {
        const float* vR = (mat == 0) ? v2L : v1L;
        const float* vL = (mat == 1) ? v1L : v2L;
        const float* Gm = G + mat * 16384;
        float tv[16];
#pragma unroll
        for (int rr = 0; rr < 16; ++rr) tv[rr] = 0.f;
        for (int k4 = 0; k4 < 128; k4 += 4) {
            const float4 gv = *reinterpret_cast<const float4*>(&Gm[o * 128 + k4]);
#pragma unroll
            for (int rr = 0; rr < 16; ++rr) {
                const float4 uv = *reinterpret_cast<const float4*>(&vR[(rb + rr * 2) * 132 + k4]);
                tv[rr] += uv.x * gv.x + uv.y * gv.y + uv.z * gv.z + uv.w * gv.w;
            }
        }
        __syncthreads();
#pragma unroll
        for (int rr = 0; rr < 16; ++rr) {
            int rw = rb + rr * 2;
            tL[rw * 132 + o] = vL[rw * 132 + o] * tv[rr];
        }
        __syncthreads();
        float p = 0.f;
#pragma unroll
        for (int kk = 0; kk < 16; ++kk) p += tL[rA * 132 + sA + kk * 8];
        p = red8(p);
        if (sA == 0) RCX[mat][rA] = p;
    }
    __syncthreads();
    if (tid < 32) {
        const int row = rblk + tid;
        const float R = RCX[0][tid], Cc = RCX[1][tid], X = RCX[2][tid];
        const float xn1v = xn1[row], xn2v = xn2[row];
        const float mxn1 = fmaxf(sqrtf(fmaxf(R, 0.f)), 1e-15f);
        const float t1 = tanhf(mxn1 / xn2v * artanh_clip(xn2v));
        const float f1 = t1 / mxn1;
        const float mxn2 = fmaxf(sqrtf(fmaxf(Cc, 0.f)), 1e-15f);
        const float t2 = tanhf(mxn2 / xn1v * artanh_clip(xn1v));
        const float f2 = t2 / mxn2;
        const float x2 = f1 * f1 * R, y2 = f2 * f2 * Cc;
        const float xy = -f1 * f2 * X;
        const float rden = 1.f / fmaxf(1.f + 2.f * xy + x2 * y2, 1e-15f);
        P[row] = (1.f + 2.f * xy + y2) * f1 * rden;
        Q[row] = -(1.f - x2) * f2 * rden;
    }
}

// ---------------------------------------------------------------- fused -----
// grid 256, block 1024 (16 waves). Block owns i-rows i0..i0+31; wave w covers
// j-steps {(w + 16t)*32, t=0..15}. Barrier-free main loop (see R5); epilogue
// LDS atomicAdd combine + fused row-normalize/logmap0 -> out.
__global__ __launch_bounds__(1024) void fused_kernel(
    const unsigned short* __restrict__ nv1b, const unsigned short* __restrict__ nv2b,
    const unsigned short* __restrict__ xtT,
    const float* __restrict__ P, const float* __restrict__ Q,
    float* __restrict__ out) {
    __shared__ float UL[32 * 132];
    __shared__ float rsL[32], qL[32];

    const int tid = threadIdx.x;
    const int w = tid >> 6, l = tid & 63;
    const int g = l >> 4, c = l & 15;
    const int i0 = blockIdx.x * 32;

    for (int i = tid; i < 32 * 132; i += 1024) UL[i] = 0.f;
    if (tid < 32) { rsL[tid] = 0.f; qL[tid] = 0.f; }
    __syncthreads();

    const float Pv0 = P[i0 + c], Pv1 = P[i0 + 16 + c];
    const float Qv0 = Q[i0 + c], Qv1 = Q[i0 + 16 + c];
    const bool needS2 = __any((fabsf(Qv0) > 1e-6f) || (fabsf(Qv1) > 1e-6f)) != 0;

    // persistent nv2 B-frags (B[k=d][n=i]): lane reads nv2[i0(+16)+c][d-slice]
    short8 Bn0[4], Bn1[4];
#pragma unroll
    for (int kk = 0; kk < 4; ++kk) {
        Bn0[kk] = *reinterpret_cast<const short8*>(nv2b + (i0 + c) * 128 + kk * 32 + g * 8);
        Bn1[kk] = *reinterpret_cast<const short8*>(nv2b + (i0 + 16 + c) * 128 + kk * 32 + g * 8);
    }

    const f32x4 z4 = {0.f, 0.f, 0.f, 0.f};
    f32x4 accU0[8], accU1[8];
#pragma unroll
    for (int ft = 0; ft < 8; ++ft) { accU0[ft] = z4; accU1[ft] = z4; }
    float rs0 = 0.f, rs1 = 0.f, q0 = 0.f, q1 = 0.f;

    // permuted A row offset: tile0 row perm(c)=8*(c>>2)+(c&3); tile1 = +4
    const int aoff = (8 * (c >> 2) + (c & 3)) * 128 + g * 8;
    const int sdiag = i0 >> 5;
    const int tdiag = ((sdiag & 15) == w) ? (sdiag >> 4) : -1;
    const size_t xoff = (size_t)c * 8192 + g * 8;

    auto elem = [&](float s, float s2v, float Pv, float Qv, int jglob, int iglob,
                    bool dd, float& rsa, float& qa) -> float {
        float a = Pv * s;
        if (needS2) a = fmaf(Qv, s2v, a);
        float e = __builtin_amdgcn_exp2f(a * 8.65617025f);
        float t = 1.0f - 2.0f * __builtin_amdgcn_rcpf(e + 1.0f);
        float ad = fmaxf(t, 0.0f);
        if (dd && (jglob == iglob)) ad += 1e-4f;
        rsa += ad;
        qa = fmaf(ad, ad, qa);
        return ad;
    };
    auto pack8 = [](const float* ad) -> short8 {
        union { unsigned u[4]; short8 s; } r;
#pragma unroll
        for (int k = 0; k < 4; ++k)
            r.u[k] = (unsigned)f2bf(ad[2 * k]) | ((unsigned)f2bf(ad[2 * k + 1]) << 16);
        return r.s;
    };

    auto doStep = [&](int jb, bool dd) __attribute__((always_inline)) {
        const unsigned short* pa = nv1b + (size_t)jb * 128;
        short8 A0[4], A1[4];
#pragma unroll
        for (int kk = 0; kk < 4; ++kk) {
            A0[kk] = *reinterpret_cast<const short8*>(pa + aoff + kk * 32);
            A1[kk] = *reinterpret_cast<const short8*>(pa + aoff + 512 + kk * 32);
        }
        // S^T tiles: sXY -> X = j-tile (0/1), Y = i-subtile (0/1)
        f32x4 s00 = z4, s10 = z4, s01 = z4, s11 = z4;
#pragma unroll
        for (int kk = 0; kk < 4; ++kk) {
            s00 = __builtin_amdgcn_mfma_f32_16x16x32_bf16(A0[kk], Bn0[kk], s00, 0, 0, 0);
            s10 = __builtin_amdgcn_mfma_f32_16x16x32_bf16(A1[kk], Bn0[kk], s10, 0, 0, 0);
            s01 = __builtin_amdgcn_mfma_f32_16x16x32_bf16(A0[kk], Bn1[kk], s01, 0, 0, 0);
            s11 = __builtin_amdgcn_mfma_f32_16x16x32_bf16(A1[kk], Bn1[kk], s11, 0, 0, 0);
        }
        // rare exact path: S2[i][j] = nv1_i . nv2_j  (same permuted structure)
        f32x4 r00 = z4, r10 = z4, r01 = z4, r11 = z4;
        if (needS2) {
            const unsigned short* pa2 = nv2b + (size_t)jb * 128;
            short8 C0[4], C1[4], D0[4], D1[4];
#pragma unroll
            for (int kk = 0; kk < 4; ++kk) {
                C0[kk] = *reinterpret_cast<const short8*>(pa2 + aoff + kk * 32);
                C1[kk] = *reinterpret_cast<const short8*>(pa2 + aoff + 512 + kk * 32);
                D0[kk] = *reinterpret_cast<const short8*>(nv1b + (i0 + c) * 128 + kk * 32 + g * 8);
                D1[kk] = *reinterpret_cast<const short8*>(nv1b + (i0 + 16 + c) * 128 + kk * 32 + g * 8);
            }
#pragma unroll
            for (int kk = 0; kk < 4; ++kk) {
                r00 = __builtin_amdgcn_mfma_f32_16x16x32_bf16(C0[kk], D0[kk], r00, 0, 0, 0);
                r10 = __builtin_amdgcn_mfma_f32_16x16x32_bf16(C1[kk], D0[kk], r10, 0, 0, 0);
                r01 = __builtin_amdgcn_mfma_f32_16x16x32_bf16(C0[kk], D1[kk], r01, 0, 0, 0);
                r11 = __builtin_amdgcn_mfma_f32_16x16x32_bf16(C1[kk], D1[kk], r11, 0, 0, 0);
            }
        }
        // transform -> adj (e-th element of lane (g,c) is j = jb + 8g + e)
        float ad0[8], ad1[8];
        const int jg = jb + 8 * g;
        const int ig0 = i0 + c, ig1 = i0 + 16 + c;
#pragma unroll
        for (int v = 0; v < 4; ++v) {
            ad0[v]     = elem(s00[v], r00[v], Pv0, Qv0, jg + v,     ig0, dd, rs0, q0);
            ad0[4 + v] = elem(s10[v], r10[v], Pv0, Qv0, jg + 4 + v, ig0, dd, rs0, q0);
            ad1[v]     = elem(s01[v], r01[v], Pv1, Qv1, jg + v,     ig1, dd, rs1, q1);
            ad1[4 + v] = elem(s11[v], r11[v], Pv1, Qv1, jg + 4 + v, ig1, dd, rs1, q1);
        }
        const short8 af0 = pack8(ad0);
        const short8 af1 = pack8(ad1);
        // PV: U[i][f] += adj[i][j] * xt[j][f]
#pragma unroll
        for (int ft = 0; ft < 8; ++ft) {
            short8 xb = *reinterpret_cast<const short8*>(xtT + (size_t)ft * 16 * 8192 + xoff + jb);
            accU0[ft] = __builtin_amdgcn_mfma_f32_16x16x32_bf16(af0, xb, accU0[ft], 0, 0, 0);
            accU1[ft] = __builtin_amdgcn_mfma_f32_16x16x32_bf16(af1, xb, accU1[ft], 0, 0, 0);
        }
    };

    for (int t = 0; t < 16; ++t) {
        const int jb = (w + 16 * t) * 32;
        if (t == tdiag) doStep(jb, true);
        else doStep(jb, false);
    }

    // ---- combine across waves (LDS atomics), then fused finalize ----
    rs0 += __shfl_xor(rs0, 16); rs0 += __shfl_xor(rs0, 32);
    rs1 += __shfl_xor(rs1, 16); rs1 += __shfl_xor(rs1, 32);
    q0 += __shfl_xor(q0, 16);   q0 += __shfl_xor(q0, 32);
    q1 += __shfl_xor(q1, 16);   q1 += __shfl_xor(q1, 32);
    if (l < 16) {
        atomicAdd(&rsL[c], rs0);
        atomicAdd(&qL[c], q0);
        atomicAdd(&rsL[16 + c], rs1);
        atomicAdd(&qL[16 + c], q1);
    }
#pragma unroll
    for (int ft = 0; ft < 8; ++ft)
#pragma unroll
        for (int v = 0; v < 4; ++v) {
            atomicAdd(&UL[(4 * g + v) * 132 + ft * 16 + c], accU0[ft][v]);
            atomicAdd(&UL[(16 + 4 * g + v) * 132 + ft * 16 + c], accU1[ft][v]);
        }
    __syncthreads();

    // finalize: 32 rows x 128 cols; 16 threads/row x 8 elems (first 512 thr)
    if (tid < 512) {
        const int r = tid >> 4, cc = tid & 15;
        const float rsv = rsL[r];
        const float wv = (rsv == 0.f) ? 0.f : 1.f / rsv;
        float m[8];
        float m2 = 0.f;
#pragma unroll
        for (int e = 0; e < 8; ++e) {
            m[e] = UL[r * 132 + cc * 8 + e] * wv;
            m2 = fmaf(m[e], m[e], m2);
        }
        m2 += __shfl_xor(m2, 1);
        m2 += __shfl_xor(m2, 2);
        m2 += __shfl_xor(m2, 4);
        m2 += __shfl_xor(m2, 8);
        const float mxn = fmaxf(sqrtf(m2), 1e-15f);
        const float xn = fmaxf(sqrtf(fmaxf(qL[r], 0.f)) * wv, 1e-15f);
        const float tt = tanhf(mxn / xn * artanh_clip(xn));
        const float nres = fmaxf(tt, 1e-15f);
        const float lsc = (tt / mxn) * (artanh_clip(nres) / nres);
        float4 o0 = {m[0] * lsc, m[1] * lsc, m[2] * lsc, m[3] * lsc};
        float4 o1 = {m[4] * lsc, m[5] * lsc, m[6] * lsc, m[7] * lsc};
        *reinterpret_cast<float4*>(out + (i0 + r) * 128 + cc * 8) = o0;
        *reinterpret_cast<float4*>(out + (i0 + r) * 128 + cc * 8 + 4) = o1;
    }
}

// ---------------------------------------------------------------- launch ----
extern "C" void kernel_launch(void* const* d_in, const int* in_sizes, int n_in,
                              void* d_out, int out_size, void* d_ws, size_t ws_size,
                              hipStream_t stream) {
    const int* idx = (const int*)d_in[0];
    const float* x = (const float*)d_in[2];
    const float* emb1 = (const float*)d_in[3];
    const float* emb2 = (const float*)d_in[4];
    const float* W1 = (const float*)d_in[5];
    const float* b1 = (const float*)d_in[6];
    const float* W2 = (const float*)d_in[7];
    const float* b2 = (const float*)d_in[8];
    float* out = (float*)d_out;
    char* ws = (char*)d_ws;

    // ws footprint: 6.6MB (safe: R1/R2 proved >= ~8.7MB)
    unsigned short* nv1b = (unsigned short*)(ws + 0x000000);   // 2MB bf16 [8192][128]
    unsigned short* nv2b = (unsigned short*)(ws + 0x200000);   // 2MB
    unsigned short* xtT = (unsigned short*)(ws + 0x400000);    // 2MB bf16 [128][8192]
    float* G = (float*)(ws + 0x600000);                        // 3 x 128x128 fp32
    float* xn1 = (float*)(ws + 0x630000);
    float* xn2 = (float*)(ws + 0x638000);
    float* P = (float*)(ws + 0x640000);
    float* Q = (float*)(ws + 0x648000);

    hipMemsetAsync(G, 0, 3 * 128 * 128 * sizeof(float), stream);
    prep_kernel<<<dim3(256, 3), 256, 0, stream>>>(idx, x, emb1, emb2, W1, W2, b1, b2,
                                                  nv1b, nv2b, xtT, xn1, xn2);
    gram_kernel<<<dim3(16, 3, 8), 256, 0, stream>>>(nv1b, nv2b, G);
    rowcoef_kernel<<<256, 256, 0, stream>>>(G, xn1, xn2, nv1b, nv2b, P, Q);
    fused_kernel<<<256, 1024, 0, stream>>>(nv1b, nv2b, xtT, P, Q, out);
    (void)in_sizes; (void)n_in; (void)out_size; (void)ws_size; (void)d_in;
}

// Round 7
// 334.613 us; speedup vs baseline: 1.4077x; 1.4077x over previous
//
#include <hip/hip_runtime.h>
#include <hip/hip_bf16.h>

// HyperbolicGraphConstructor R7:
//  - fused_kernel: R5's 512-thread barrier-free structure + software pipeline:
//    uniform branchless j-loop (diag handled exactly via epilogue correction
//    with precomputed Ad from rowcoef), current-step XB loads + next-step A
//    loads issued at step top so L2 latency hides under MFMA+VALU.
//  - rowcoef additionally computes d_i = nv1_i.nv2_i and Ad_i = relu(tanh(3(P+Q)d)).
//  - R6's 1024-thread experiment reverted (spill: 4-wave/SIMD min -> 128-reg cap).

typedef __attribute__((ext_vector_type(8))) short short8;
typedef __attribute__((ext_vector_type(4))) float f32x4;

#define MAXN 0.996f   /* (1 - 4e-3)/sqrt(c) */

__device__ __forceinline__ float artanh_clip(float x) {
    x = fminf(x, 1.0f - 1e-7f);
    x = fmaxf(x, -1.0f + 1e-7f);
    return 0.5f * logf((1.0f + x) / (1.0f - x));
}

__device__ __forceinline__ float red8(float v) {
    v += __shfl_xor(v, 1);
    v += __shfl_xor(v, 2);
    v += __shfl_xor(v, 4);
    return v;
}

__device__ __forceinline__ float red64(float v) {
#pragma unroll
    for (int m = 1; m < 64; m <<= 1) v += __shfl_xor(v, m);
    return v;
}

__device__ __forceinline__ unsigned short f2bf(float f) {
    __hip_bfloat16 h = __float2bfloat16(f);
    return *reinterpret_cast<unsigned short*>(&h);
}

__device__ __forceinline__ float bf2f(unsigned short u) {
    __hip_bfloat16 h;
    *reinterpret_cast<unsigned short*>(&h) = u;
    return __bfloat162float(h);
}

// ---------------------------------------------------------------- prep ------
// grid (256, 3), block 256: y=0 -> nv1 (emb1,W1,b1); y=1 -> nv2; y=2 -> xt.
__global__ __launch_bounds__(256) void prep_kernel(
    const int* __restrict__ idx, const float* __restrict__ x,
    const float* __restrict__ emb1, const float* __restrict__ emb2,
    const float* __restrict__ W1, const float* __restrict__ W2,
    const float* __restrict__ b1, const float* __restrict__ b2,
    unsigned short* __restrict__ nv1b, unsigned short* __restrict__ nv2b,
    unsigned short* __restrict__ xtT,
    float* __restrict__ xn1, float* __restrict__ xn2) {
    const int which = blockIdx.y;
    const int tid = threadIdx.x;
    const int rblk = blockIdx.x * 32;

    if (which == 2) {
        __shared__ float xv[32 * 132];
        const int r = tid >> 3, s = tid & 7;
        float ev[16];
        float p2 = 0.f;
#pragma unroll
        for (int kk = 0; kk < 16; ++kk) {
            float e = x[(rblk + r) * 128 + s + kk * 8];
            ev[kk] = e;
            p2 += e * e;
        }
        const float n = fmaxf(sqrtf(red8(p2)), 1e-15f);
        const float scl = artanh_clip(n) / n;
#pragma unroll
        for (int kk = 0; kk < 16; ++kk) xv[r * 132 + s + kk * 8] = ev[kk] * scl;
        __syncthreads();
        const int k = tid >> 1, h = tid & 1;
        short8 o0, o1;
#pragma unroll
        for (int j = 0; j < 8; ++j) o0[j] = (short)f2bf(xv[(h * 16 + j) * 132 + k]);
#pragma unroll
        for (int j = 0; j < 8; ++j) o1[j] = (short)f2bf(xv[(h * 16 + 8 + j) * 132 + k]);
        *reinterpret_cast<short8*>(&xtT[k * 8192 + rblk + h * 16]) = o0;
        *reinterpret_cast<short8*>(&xtT[k * 8192 + rblk + h * 16 + 8]) = o1;
        return;
    }

    __shared__ __align__(16) float uL[32 * 132];
    __shared__ float mxL[32 * 132];
    __shared__ float xnL[32];
    __shared__ float hbL[128];
    __shared__ float s2s[4];

    const float* emb = which ? emb2 : emb1;
    const float* W = which ? W2 : W1;
    const float* b = which ? b2 : b1;
    unsigned short* nvb = which ? nv2b : nv1b;
    float* xno = which ? xn2 : xn1;

    float bv = (tid < 128) ? b[tid] : 0.f;
    float ssq = red64(bv * bv);
    if ((tid & 63) == 0) s2s[tid >> 6] = ssq;
    __syncthreads();
    const float bn = fmaxf(sqrtf(s2s[0] + s2s[1]), 1e-15f);
    const float bth = tanhf(bn);
    const float bnu = fmaxf(bth, 1e-15f);
    const float bps = (bnu > MAXN) ? (MAXN / bnu) : 1.0f;
    if (tid < 128) hbL[tid] = bv * (bth / bn) * bps;
    const float hbn = fminf(bnu, MAXN);
    const float y2 = hbn * hbn;

    const int r = tid >> 3, s = tid & 7;
    const int row = rblk + r;
    const int src = idx[row];
    float ev[16];
    float p2 = 0.f;
#pragma unroll
    for (int kk = 0; kk < 16; ++kk) {
        float e = emb[src * 128 + s + kk * 8];
        ev[kk] = e;
        p2 += e * e;
    }
    float n2 = red8(p2);
    float n = fmaxf(sqrtf(n2), 1e-15f);
    float th = tanhf(n);
    float nu = fmaxf(th, 1e-15f);
    float ps = (nu > MAXN) ? (MAXN / nu) : 1.0f;
    float sc0 = (th / n) * ps;
#pragma unroll
    for (int kk = 0; kk < 16; ++kk) uL[r * 132 + s + kk * 8] = ev[kk] * sc0;
    if (s == 0) xnL[r] = fmaxf(nu * ps, 1e-15f);
    __syncthreads();

    const int o = tid & 127, rb = tid >> 7;
    float mxv[16];
#pragma unroll
    for (int rr = 0; rr < 16; ++rr) mxv[rr] = 0.f;
    for (int k4 = 0; k4 < 128; k4 += 4) {
        const float4 wv = *reinterpret_cast<const float4*>(&W[o * 128 + k4]);
#pragma unroll
        for (int rr = 0; rr < 16; ++rr) {
            const float4 uv = *reinterpret_cast<const float4*>(&uL[(rb + rr * 2) * 132 + k4]);
            mxv[rr] += uv.x * wv.x + uv.y * wv.y + uv.z * wv.z + uv.w * wv.w;
        }
    }
#pragma unroll
    for (int rr = 0; rr < 16; ++rr) mxL[(rb + rr * 2) * 132 + o] = mxv[rr];
    __syncthreads();

    float mx[16];
    float m2 = 0.f;
#pragma unroll
    for (int kk = 0; kk < 16; ++kk) {
        mx[kk] = mxL[r * 132 + s + kk * 8];
        m2 += mx[kk] * mx[kk];
    }
    float mxn = fmaxf(sqrtf(red8(m2)), 1e-15f);
    float xnv = xnL[r];
    float tt = tanhf(mxn / xnv * artanh_clip(xnv));
    float nres = fmaxf(tt, 1e-15f);
    float ps2 = (nres > MAXN) ? (MAXN / nres) : 1.0f;
    float s2 = (tt / mxn) * ps2;
    float mvn = nres * ps2;
    float x2 = mvn * mvn;
    float xyp = 0.f;
    float mv[16];
#pragma unroll
    for (int kk = 0; kk < 16; ++kk) {
        mv[kk] = mx[kk] * s2;
        xyp += mv[kk] * hbL[s + kk * 8];
    }
    float xy = red8(xyp);
    float cA = 1.f + 2.f * xy + y2;
    float cB = 1.f - x2;
    float rden = 1.f / fmaxf(1.f + 2.f * xy + x2 * y2, 1e-15f);
    float r2v[16];
    float q2 = 0.f;
#pragma unroll
    for (int kk = 0; kk < 16; ++kk) {
        float v = (cA * mv[kk] + cB * hbL[s + kk * 8]) * rden;
        r2v[kk] = v;
        q2 += v * v;
    }
    float nr2 = fmaxf(sqrtf(red8(q2)), 1e-15f);
    float ps3 = (nr2 > MAXN) ? (MAXN / nr2) : 1.0f;
#pragma unroll
    for (int kk = 0; kk < 16; ++kk) nvb[row * 128 + s + kk * 8] = f2bf(r2v[kk] * ps3);
    if (s == 0) xno[row] = fmaxf((nr2 > MAXN) ? MAXN : nr2, 1e-15f);
}

// ---------------------------------------------------------------- gram ------
__global__ __launch_bounds__(256) void gram_kernel(const unsigned short* __restrict__ nv1b,
                                                   const unsigned short* __restrict__ nv2b,
                                                   float* __restrict__ G) {
    __shared__ float Ab[64 * 33], Bb[64 * 33];
    const int tile = blockIdx.x, mat = blockIdx.y, kc = blockIdx.z;
    const int ta = (tile & 3) * 32, tb = (tile >> 2) * 32;
    const unsigned short* Am = (mat == 1) ? nv2b : nv1b;
    const unsigned short* Bm = (mat == 0) ? nv1b : nv2b;
    const int tid = threadIdx.x;
    const int oa = tid & 31, obb = (tid >> 5) * 4;
    float acc[4] = {0.f, 0.f, 0.f, 0.f};
    for (int sc = 0; sc < 16; ++sc) {
        const int r0 = kc * 1024 + sc * 64;
        for (int i0 = tid; i0 < 2048; i0 += 256) {
            int rr = i0 >> 5, cc = i0 & 31;
            Ab[rr * 33 + cc] = bf2f(Am[(r0 + rr) * 128 + ta + cc]);
            Bb[rr * 33 + cc] = bf2f(Bm[(r0 + rr) * 128 + tb + cc]);
        }
        __syncthreads();
#pragma unroll 4
        for (int rr = 0; rr < 64; ++rr) {
            float av = Ab[rr * 33 + oa];
#pragma unroll
            for (int i = 0; i < 4; ++i) acc[i] += av * Bb[rr * 33 + obb + i];
        }
        __syncthreads();
    }
#pragma unroll
    for (int i = 0; i < 4; ++i)
        atomicAdd(&G[mat * 16384 + (ta + oa) * 128 + tb + obb + i], acc[i]);
}

// ---------------------------------------------------------------- rowcoef ---
// grid 256, block 256. Computes P,Q and Ad_i = relu(tanh(3*(P_i+Q_i)*d_i)),
// d_i = nv1_i . nv2_i (diagonal of S1/S2 -> exact epilogue diag correction).
__global__ __launch_bounds__(256) void rowcoef_kernel(
    const float* __restrict__ G, const float* __restrict__ xn1, const float* __restrict__ xn2,
    const unsigned short* __restrict__ nv1b, const unsigned short* __restrict__ nv2b,
    float* __restrict__ P, float* __restrict__ Q, float* __restrict__ Ad) {
    __shared__ __align__(16) float v1L[32 * 132];
    __shared__ __align__(16) float v2L[32 * 132];
    __shared__ float tL[32 * 132];
    __shared__ float RCX[3][32];
    __shared__ float dL[32];
    const int tid = threadIdx.x;
    const int rblk = blockIdx.x * 32;
    for (int i = tid; i < 4096; i += 256) {
        int r = i >> 7, c = i & 127;
        v1L[r * 132 + c] = bf2f(nv1b[(rblk + r) * 128 + c]);
        v2L[r * 132 + c] = bf2f(nv2b[(rblk + r) * 128 + c]);
    }
    __syncthreads();
    const int o = tid & 127, rb = tid >> 7;
    const int rA = tid >> 3, sA = tid & 7;
    for (int mat = 0; mat < 3; ++mat) {
        const float* vR = (mat == 0) ? v2L : v1L;
        const float* vL = (mat == 1) ? v1L : v2L;
        const float* Gm = G + mat * 16384;
        float tv[16];
#pragma unroll
        for (int rr = 0; rr < 16; ++rr) tv[rr] = 0.f;
        for (int k4 = 0; k4 < 128; k4 += 4) {
            const float4 gv = *reinterpret_cast<const float4*>(&Gm[o * 128 + k4]);
#pragma unroll
            for (int rr = 0; rr < 16; ++rr) {
                const float4 uv = *reinterpret_cast<const float4*>(&vR[(rb + rr * 2) * 132 + k4]);
                tv[rr] += uv.x * gv.x + uv.y * gv.y + uv.z * gv.z + uv.w * gv.w;
            }
        }
        __syncthreads();
#pragma unroll
        for (int rr = 0; rr < 16; ++rr) {
            int rw = rb + rr * 2;
            tL[rw * 132 + o] = vL[rw * 132 + o] * tv[rr];
        }
        __syncthreads();
        float p = 0.f;
#pragma unroll
        for (int kk = 0; kk < 16; ++kk) p += tL[rA * 132 + sA + kk * 8];
        p = red8(p);
        if (sA == 0) RCX[mat][rA] = p;
    }
    // row dot d_i = nv1_i . nv2_i
    float dp = 0.f;
#pragma unroll
    for (int kk = 0; kk < 16; ++kk)
        dp += v1L[rA * 132 + sA + kk * 8] * v2L[rA * 132 + sA + kk * 8];
    dp = red8(dp);
    if (sA == 0) dL[rA] = dp;
    __syncthreads();
    if (tid < 32) {
        const int row = rblk + tid;
        const float R = RCX[0][tid], Cc = RCX[1][tid], X = RCX[2][tid];
        const float xn1v = xn1[row], xn2v = xn2[row];
        const float mxn1 = fmaxf(sqrtf(fmaxf(R, 0.f)), 1e-15f);
        const float t1 = tanhf(mxn1 / xn2v * artanh_clip(xn2v));
        const float f1 = t1 / mxn1;
        const float mxn2 = fmaxf(sqrtf(fmaxf(Cc, 0.f)), 1e-15f);
        const float t2 = tanhf(mxn2 / xn1v * artanh_clip(xn1v));
        const float f2 = t2 / mxn2;
        const float x2 = f1 * f1 * R, y2 = f2 * f2 * Cc;
        const float xy = -f1 * f2 * X;
        const float rden = 1.f / fmaxf(1.f + 2.f * xy + x2 * y2, 1e-15f);
        const float Pv = (1.f + 2.f * xy + y2) * f1 * rden;
        const float Qv = -(1.f - x2) * f2 * rden;
        P[row] = Pv;
        Q[row] = Qv;
        Ad[row] = fmaxf(tanhf(3.f * (Pv + Qv) * dL[tid]), 0.f);
    }
}

// ---------------------------------------------------------------- fused -----
// grid 256, block 512 (8 waves). Block owns i-rows i0..i0+31; wave w covers
// j-steps {(w + 8t)*32, t=0..31}. Branchless software-pipelined loop:
// step top issues current XB loads + next-step A loads; S^T MFMA consumes
// A preloaded last step. Diag bump applied exactly in epilogue via Ad.
__global__ __launch_bounds__(512) void fused_kernel(
    const unsigned short* __restrict__ nv1b, const unsigned short* __restrict__ nv2b,
    const unsigned short* __restrict__ xtT,
    const float* __restrict__ P, const float* __restrict__ Q,
    const float* __restrict__ Ad,
    float* __restrict__ out) {
    __shared__ float UL[32 * 132];
    __shared__ float rsL[32], qL[32];

    const int tid = threadIdx.x;
    const int w = tid >> 6, l = tid & 63;
    const int g = l >> 4, c = l & 15;
    const int i0 = blockIdx.x * 32;

    for (int i = tid; i < 32 * 132; i += 512) UL[i] = 0.f;
    if (tid < 32) { rsL[tid] = 0.f; qL[tid] = 0.f; }
    __syncthreads();

    const float Pv0 = P[i0 + c], Pv1 = P[i0 + 16 + c];
    const float Qv0 = Q[i0 + c], Qv1 = Q[i0 + 16 + c];
    const bool needS2 = __any((fabsf(Qv0) > 1e-6f) || (fabsf(Qv1) > 1e-6f)) != 0;

    // persistent nv2 B-frags (B[k=d][n=i])
    short8 Bn0[4], Bn1[4];
#pragma unroll
    for (int kk = 0; kk < 4; ++kk) {
        Bn0[kk] = *reinterpret_cast<const short8*>(nv2b + (i0 + c) * 128 + kk * 32 + g * 8);
        Bn1[kk] = *reinterpret_cast<const short8*>(nv2b + (i0 + 16 + c) * 128 + kk * 32 + g * 8);
    }

    const f32x4 z4 = {0.f, 0.f, 0.f, 0.f};
    f32x4 accU0[8], accU1[8];
#pragma unroll
    for (int ft = 0; ft < 8; ++ft) { accU0[ft] = z4; accU1[ft] = z4; }
    float rs0 = 0.f, rs1 = 0.f, q0 = 0.f, q1 = 0.f;

    // permuted A row offset: tile0 row perm(c)=8*(c>>2)+(c&3); tile1 = +4
    const int aoff = (8 * (c >> 2) + (c & 3)) * 128 + g * 8;
    const size_t xoff = (size_t)c * 8192 + g * 8;

    auto elem = [&](float s, float s2v, float Pv, float Qv,
                    float& rsa, float& qa) -> float {
        float a = Pv * s;
        if (needS2) a = fmaf(Qv, s2v, a);
        float e = __builtin_amdgcn_exp2f(a * 8.65617025f);
        float t = 1.0f - 2.0f * __builtin_amdgcn_rcpf(e + 1.0f);
        float ad = fmaxf(t, 0.0f);
        rsa += ad;
        qa = fmaf(ad, ad, qa);
        return ad;
    };
    auto pack8 = [](const float* ad) -> short8 {
        union { unsigned u[4]; short8 s; } r;
#pragma unroll
        for (int k = 0; k < 4; ++k)
            r.u[k] = (unsigned)f2bf(ad[2 * k]) | ((unsigned)f2bf(ad[2 * k + 1]) << 16);
        return r.s;
    };

    // software pipeline: preload A-frags for step 0
    short8 A0c[4], A1c[4];
    {
        const unsigned short* pa0 = nv1b + (size_t)(w * 32) * 128;
#pragma unroll
        for (int kk = 0; kk < 4; ++kk) {
            A0c[kk] = *reinterpret_cast<const short8*>(pa0 + aoff + kk * 32);
            A1c[kk] = *reinterpret_cast<const short8*>(pa0 + aoff + 512 + kk * 32);
        }
    }

    for (int t = 0; t < 32; ++t) {
        const int jb = (w + 8 * t) * 32;
        const int jbn = (w + 8 * ((t + 1) & 31)) * 32;  // wraps -> always valid

        // issue current-step xt loads early (used at PV, ~600cy later)
        short8 XB[8];
#pragma unroll
        for (int ft = 0; ft < 8; ++ft)
            XB[ft] = *reinterpret_cast<const short8*>(xtT + (size_t)ft * 16 * 8192 + xoff + jb);
        // issue next-step A loads (used at next step's S-MFMA)
        short8 A0n[4], A1n[4];
        {
            const unsigned short* pan = nv1b + (size_t)jbn * 128;
#pragma unroll
            for (int kk = 0; kk < 4; ++kk) {
                A0n[kk] = *reinterpret_cast<const short8*>(pan + aoff + kk * 32);
                A1n[kk] = *reinterpret_cast<const short8*>(pan + aoff + 512 + kk * 32);
            }
        }

        // S^T tiles on preloaded A: sXY -> X = j-tile (0/1), Y = i-subtile (0/1)
        f32x4 s00 = z4, s10 = z4, s01 = z4, s11 = z4;
#pragma unroll
        for (int kk = 0; kk < 4; ++kk) {
            s00 = __builtin_amdgcn_mfma_f32_16x16x32_bf16(A0c[kk], Bn0[kk], s00, 0, 0, 0);
            s10 = __builtin_amdgcn_mfma_f32_16x16x32_bf16(A1c[kk], Bn0[kk], s10, 0, 0, 0);
            s01 = __builtin_amdgcn_mfma_f32_16x16x32_bf16(A0c[kk], Bn1[kk], s01, 0, 0, 0);
            s11 = __builtin_amdgcn_mfma_f32_16x16x32_bf16(A1c[kk], Bn1[kk], s11, 0, 0, 0);
        }
        // rare exact path: S2[i][j] = nv1_i . nv2_j  (same permuted structure)
        f32x4 r00 = z4, r10 = z4, r01 = z4, r11 = z4;
        if (needS2) {
            const unsigned short* pa2 = nv2b + (size_t)jb * 128;
            short8 C0[4], C1[4], D0[4], D1[4];
#pragma unroll
            for (int kk = 0; kk < 4; ++kk) {
                C0[kk] = *reinterpret_cast<const short8*>(pa2 + aoff + kk * 32);
                C1[kk] = *reinterpret_cast<const short8*>(pa2 + aoff + 512 + kk * 32);
                D0[kk] = *reinterpret_cast<const short8*>(nv1b + (i0 + c) * 128 + kk * 32 + g * 8);
                D1[kk] = *reinterpret_cast<const short8*>(nv1b + (i0 + 16 + c) * 128 + kk * 32 + g * 8);
            }
#pragma unroll
            for (int kk = 0; kk < 4; ++kk) {
                r00 = __builtin_amdgcn_mfma_f32_16x16x32_bf16(C0[kk], D0[kk], r00, 0, 0, 0);
                r10 = __builtin_amdgcn_mfma_f32_16x16x32_bf16(C1[kk], D0[kk], r10, 0, 0, 0);
                r01 = __builtin_amdgcn_mfma_f32_16x16x32_bf16(C0[kk], D1[kk], r01, 0, 0, 0);
                r11 = __builtin_amdgcn_mfma_f32_16x16x32_bf16(C1[kk], D1[kk], r11, 0, 0, 0);
            }
        }

        // transform -> adj (branchless; diag corrected in epilogue)
        float ad0[8], ad1[8];
#pragma unroll
        for (int v = 0; v < 4; ++v) {
            ad0[v]     = elem(s00[v], r00[v], Pv0, Qv0, rs0, q0);
            ad0[4 + v] = elem(s10[v], r10[v], Pv0, Qv0, rs0, q0);
            ad1[v]     = elem(s01[v], r01[v], Pv1, Qv1, rs1, q1);
            ad1[4 + v] = elem(s11[v], r11[v], Pv1, Qv1, rs1, q1);
        }
        const short8 af0 = pack8(ad0);
        const short8 af1 = pack8(ad1);
        // PV: U[i][f] += adj[i][j] * xt[j][f]
#pragma unroll
        for (int ft = 0; ft < 8; ++ft) {
            accU0[ft] = __builtin_amdgcn_mfma_f32_16x16x32_bf16(af0, XB[ft], accU0[ft], 0, 0, 0);
            accU1[ft] = __builtin_amdgcn_mfma_f32_16x16x32_bf16(af1, XB[ft], accU1[ft], 0, 0, 0);
        }
        // rotate pipeline regs
#pragma unroll
        for (int kk = 0; kk < 4; ++kk) { A0c[kk] = A0n[kk]; A1c[kk] = A1n[kk]; }
    }

    // ---- combine across waves (LDS atomics), then fused finalize ----
    rs0 += __shfl_xor(rs0, 16); rs0 += __shfl_xor(rs0, 32);
    rs1 += __shfl_xor(rs1, 16); rs1 += __shfl_xor(rs1, 32);
    q0 += __shfl_xor(q0, 16);   q0 += __shfl_xor(q0, 32);
    q1 += __shfl_xor(q1, 16);   q1 += __shfl_xor(q1, 32);
    if (l < 16) {
        atomicAdd(&rsL[c], rs0);
        atomicAdd(&qL[c], q0);
        atomicAdd(&rsL[16 + c], rs1);
        atomicAdd(&qL[16 + c], q1);
    }
#pragma unroll
    for (int ftx = 0; ftx < 8; ++ftx) {
        const int ft = (ftx + w) & 7;  // stagger waves across banks/addresses
#pragma unroll
        for (int v = 0; v < 4; ++v) {
            atomicAdd(&UL[(4 * g + v) * 132 + ft * 16 + c], accU0[ft][v]);
            atomicAdd(&UL[(16 + 4 * g + v) * 132 + ft * 16 + c], accU1[ft][v]);
        }
    }
    __syncthreads();

    // finalize: 32 rows x 128 cols; 16 threads/row x 8 elems.
    // Exact diag correction: rs += 1e-4; qs += 2e-4*Ad + 1e-8; U += 1e-4*xt_i.
    const int r = tid >> 4, cc = tid & 15;
    const float adg = Ad[i0 + r];
    const float rsv = rsL[r] + 1e-4f;
    const float wv = 1.f / rsv;
    float m[8];
    float m2 = 0.f;
#pragma unroll
    for (int e = 0; e < 8; ++e) {
        const float xv = bf2f(xtT[(size_t)(cc * 8 + e) * 8192 + i0 + r]);
        m[e] = (UL[r * 132 + cc * 8 + e] + 1e-4f * xv) * wv;
        m2 = fmaf(m[e], m[e], m2);
    }
    m2 += __shfl_xor(m2, 1);
    m2 += __shfl_xor(m2, 2);
    m2 += __shfl_xor(m2, 4);
    m2 += __shfl_xor(m2, 8);
    const float mxn = fmaxf(sqrtf(m2), 1e-15f);
    const float qv = fmaxf(qL[r] + 2e-4f * adg + 1e-8f, 0.f);
    const float xn = fmaxf(sqrtf(qv) * wv, 1e-15f);
    const float tt = tanhf(mxn / xn * artanh_clip(xn));
    const float nres = fmaxf(tt, 1e-15f);
    const float lsc = (tt / mxn) * (artanh_clip(nres) / nres);
    float4 o0 = {m[0] * lsc, m[1] * lsc, m[2] * lsc, m[3] * lsc};
    float4 o1 = {m[4] * lsc, m[5] * lsc, m[6] * lsc, m[7] * lsc};
    *reinterpret_cast<float4*>(out + (i0 + r) * 128 + cc * 8) = o0;
    *reinterpret_cast<float4*>(out + (i0 + r) * 128 + cc * 8 + 4) = o1;
}

// ---------------------------------------------------------------- launch ----
extern "C" void kernel_launch(void* const* d_in, const int* in_sizes, int n_in,
                              void* d_out, int out_size, void* d_ws, size_t ws_size,
                              hipStream_t stream) {
    const int* idx = (const int*)d_in[0];
    const float* x = (const float*)d_in[2];
    const float* emb1 = (const float*)d_in[3];
    const float* emb2 = (const float*)d_in[4];
    const float* W1 = (const float*)d_in[5];
    const float* b1 = (const float*)d_in[6];
    const float* W2 = (const float*)d_in[7];
    const float* b2 = (const float*)d_in[8];
    float* out = (float*)d_out;
    char* ws = (char*)d_ws;

    // ws footprint: ~6.6MB (safe: R1/R2 proved >= ~8.7MB)
    unsigned short* nv1b = (unsigned short*)(ws + 0x000000);   // 2MB bf16 [8192][128]
    unsigned short* nv2b = (unsigned short*)(ws + 0x200000);   // 2MB
    unsigned short* xtT = (unsigned short*)(ws + 0x400000);    // 2MB bf16 [128][8192]
    float* G = (float*)(ws + 0x600000);                        // 3 x 128x128 fp32
    float* xn1 = (float*)(ws + 0x630000);
    float* xn2 = (float*)(ws + 0x638000);
    float* P = (float*)(ws + 0x640000);
    float* Q = (float*)(ws + 0x648000);
    float* Ad = (float*)(ws + 0x650000);

    hipMemsetAsync(G, 0, 3 * 128 * 128 * sizeof(float), stream);
    prep_kernel<<<dim3(256, 3), 256, 0, stream>>>(idx, x, emb1, emb2, W1, W2, b1, b2,
                                                  nv1b, nv2b, xtT, xn1, xn2);
    gram_kernel<<<dim3(16, 3, 8), 256, 0, stream>>>(nv1b, nv2b, G);
    rowcoef_kernel<<<256, 256, 0, stream>>>(G, xn1, xn2, nv1b, nv2b, P, Q, Ad);
    fused_kernel<<<256, 512, 0, stream>>>(nv1b, nv2b, xtT, P, Q, Ad, out);
    (void)in_sizes; (void)n_in; (void)out_size; (void)ws_size; (void)d_in;
}